// Round 8
// baseline (223.769 us; speedup 1.0000x reference)
//
#include <hip/hip_runtime.h>

#define N_NODES 100000
#define N_EDGES 1600000
#define F 128
#define M_PAD 100032          // 1563 blocks * 64 rows
#define GEMM_GRID 1563

#define BUCKET_BITS 9
#define BUCKET_SIZE 512
#define NBUCKETS 196          // ceil(100000/512)
#define BCAP 9216             // fixed bucket capacity (mean 8192, +11 sigma)
#define EPB_A 8192
#define ABLOCKS 196

#define AS1 __attribute__((address_space(1)))
#define AS3 __attribute__((address_space(3)))

typedef __attribute__((ext_vector_type(8))) short short8;
typedef __attribute__((ext_vector_type(4))) float f32x4;

__device__ __forceinline__ float bf_lo(unsigned int u) { return __uint_as_float(u << 16); }
__device__ __forceinline__ float bf_hi(unsigned int u) { return __uint_as_float(u & 0xffff0000u); }
__device__ __forceinline__ unsigned short f2bf(float f) {
    unsigned int u = __float_as_uint(f);
    u += 0x7fffu + ((u >> 16) & 1u);   // round-to-nearest-even
    return (unsigned short)(u >> 16);
}
__device__ __forceinline__ void gload_lds16(const void* g, void* l) {
    __builtin_amdgcn_global_load_lds((const AS1 unsigned int*)g, (AS3 unsigned int*)l, 16, 0, 0);
}

// ---------------- prep: Wt0 (swizzled), Wt1 (linear), cursor zero ----------------
__global__ __launch_bounds__(256) void prep_kernel(const float* __restrict__ W0,
                                                   const float* __restrict__ W1,
                                                   unsigned short* __restrict__ Wt0,
                                                   unsigned short* __restrict__ Wt1,
                                                   int* __restrict__ bucket_cursor) {
    int t = threadIdx.x;
    if (blockIdx.x == 2) {
        if (t < NBUCKETS) bucket_cursor[t] = 0;
        return;
    }
    int c = t & 127;
    int o0 = (t >> 7) * 8;
    if (blockIdx.x == 0) {
        // Wt0: transposed + XOR-swizzled rows (for gload_lds staging in gemm0)
        for (int o = o0; o < o0 + 8; ++o) {
            short8 v;
#pragma unroll
            for (int e = 0; e < 8; ++e) v[e] = (short)f2bf(W0[(o * 8 + e) * 128 + c]);
            *(short8*)((char*)Wt0 + c * 256 + ((o * 16) ^ ((c & 7) << 4))) = v;
        }
    } else {
        // Wt1: transposed, LINEAR (read per-lane in fused kernel; L1-resident)
        for (int o = o0; o < o0 + 8; ++o) {
            short8 v;
#pragma unroll
            for (int e = 0; e < 8; ++e) v[e] = (short)f2bf(W1[(o * 8 + e) * 128 + c]);
            *(short8*)&Wt1[c * 128 + o * 8] = v;
        }
    }
}

// ---------------- K1: binA (blocks 0..195) + gemm0 (blocks 196..1758) ----------------

__device__ __forceinline__ void binA_body(char* smem, int bid,
                                          const int* __restrict__ rows,
                                          const int* __restrict__ cols,
                                          const float* __restrict__ vals,
                                          int* __restrict__ bucket_cursor,
                                          uint2* __restrict__ stage) {
    int* hist = (int*)smem;
    int* base = hist + NBUCKETS;
    int tid = threadIdx.x;
    int start = bid * EPB_A;
    int cnt = min(EPB_A, N_EDGES - start);
    for (int i = tid; i < NBUCKETS; i += 256) hist[i] = 0;
    __syncthreads();
    for (int i = tid; i < cnt; i += 256) atomicAdd(&hist[rows[start + i] >> BUCKET_BITS], 1);
    __syncthreads();
    for (int i = tid; i < NBUCKETS; i += 256) {
        int h = hist[i];
        base[i] = h ? atomicAdd(&bucket_cursor[i], h) : 0;   // zero-based cursor
        hist[i] = 0;
    }
    __syncthreads();
    for (int i = tid; i < cnt; i += 256) {
        int r = rows[start + i];
        int c = cols[start + i];
        unsigned vb = __float_as_uint(vals[start + i]);
        int b = r >> BUCKET_BITS;
        int p = b * BCAP + base[b] + atomicAdd(&hist[b], 1);
        stage[p] = make_uint2(((unsigned)(r & (BUCKET_SIZE - 1)) << 17) | (unsigned)c, vb);
    }
}

__device__ __forceinline__ void gemm0_body(char* smem, int bid,
                                           const float* __restrict__ X,
                                           const unsigned short* __restrict__ Wt0,
                                           unsigned short* __restrict__ T) {
    unsigned short* wlds = (unsigned short*)smem;            // 32 KB
    unsigned short* alds = (unsigned short*)(smem + 32768);  // 16 KB
    int tid = threadIdx.x;
    int w = tid >> 6, l = tid & 63;
    int q = l >> 4, c16 = l & 15;
    long r0 = (long)bid * 64;

#pragma unroll
    for (int i = 0; i < 8; ++i) {
        int row = w * 32 + i * 4 + q;
        gload_lds16((const char*)Wt0 + row * 256 + c16 * 16,
                    (char*)wlds + (w * 8192 + i * 1024));
    }
    // fp32 X: reg-stage, convert, swizzled ds_write_b128
#pragma unroll
    for (int i = 0; i < 4; ++i) {
        int row = i * 16 + (tid >> 4);
        int oct = tid & 15;
        long rg = r0 + row;
        if (rg > N_NODES - 1) rg = N_NODES - 1;
        const float4* xp = (const float4*)(X + rg * 128 + oct * 8);
        float4 a = xp[0], bb = xp[1];
        short8 v;
        v[0] = (short)f2bf(a.x); v[1] = (short)f2bf(a.y);
        v[2] = (short)f2bf(a.z); v[3] = (short)f2bf(a.w);
        v[4] = (short)f2bf(bb.x); v[5] = (short)f2bf(bb.y);
        v[6] = (short)f2bf(bb.z); v[7] = (short)f2bf(bb.w);
        *(short8*)((char*)alds + row * 256 + ((oct * 16) ^ ((row & 7) << 4))) = v;
    }
    __syncthreads();

    f32x4 acc[8] = {};
    int nrow = w * 16 + c16;
    int nswz = (nrow & 7) << 4;
#pragma unroll
    for (int ks = 0; ks < 4; ++ks) {
        int kb = ks * 64 + q * 16;
        short8 bfrag = *(const short8*)((const char*)alds + nrow * 256 + (kb ^ nswz));
#pragma unroll
        for (int fb = 0; fb < 8; ++fb) {
            int frow = fb * 16 + c16;
            short8 afrag = *(const short8*)((const char*)wlds + frow * 256 +
                                            (kb ^ ((frow & 7) << 4)));
            acc[fb] = __builtin_amdgcn_mfma_f32_16x16x32_bf16(afrag, bfrag, acc[fb], 0, 0, 0);
        }
    }

    long node = r0 + w * 16 + c16;
#pragma unroll
    for (int fb = 0; fb < 8; ++fb) {
        uint2 o;
        o.x = (unsigned)f2bf(acc[fb][0]) | ((unsigned)f2bf(acc[fb][1]) << 16);
        o.y = (unsigned)f2bf(acc[fb][2]) | ((unsigned)f2bf(acc[fb][3]) << 16);
        *(uint2*)((char*)T + node * 256 + fb * 32 + q * 8) = o;
    }
}

__global__ __launch_bounds__(256) void k1_kernel(const float* __restrict__ X,
                                                 const unsigned short* __restrict__ Wt0,
                                                 unsigned short* __restrict__ T,
                                                 const int* __restrict__ rows,
                                                 const int* __restrict__ cols,
                                                 const float* __restrict__ vals,
                                                 int* __restrict__ bucket_cursor,
                                                 uint2* __restrict__ stage) {
    __shared__ char smem[49152];
    if (blockIdx.x < ABLOCKS) {
        binA_body(smem, blockIdx.x, rows, cols, vals, bucket_cursor, stage);
    } else {
        gemm0_body(smem, blockIdx.x - ABLOCKS, X, Wt0, T);
    }
}

// ---------------- binB: per-bucket counting sort by row ----------------
__global__ __launch_bounds__(1024) void binB_kernel(const uint2* __restrict__ stage,
                                                    const int* __restrict__ bucket_cursor,
                                                    uint2* __restrict__ csr,
                                                    uint2* __restrict__ rowseg) {
    __shared__ int hist[BUCKET_SIZE];
    __shared__ int scanv[BUCKET_SIZE];
    __shared__ int cur[BUCKET_SIZE];
    __shared__ int wsum[8], woff[8];
    int b = blockIdx.x;
    int t = threadIdx.x;
    int s0 = b * BCAP;
    int cnt = bucket_cursor[b];
    if (t < BUCKET_SIZE) hist[t] = 0;
    __syncthreads();
    for (int i = t; i < cnt; i += 1024) atomicAdd(&hist[stage[s0 + i].x >> 17], 1);
    __syncthreads();
    int wid = t >> 6, ln = t & 63;
    if (wid < 8) {
        int v = hist[wid * 64 + ln];
#pragma unroll
        for (int d = 1; d < 64; d <<= 1) {
            int u = __shfl_up(v, d);
            if (ln >= d) v += u;
        }
        if (ln == 63) wsum[wid] = v;
        scanv[wid * 64 + ln] = v;       // per-wave inclusive
    }
    __syncthreads();
    if (t == 0) {
        int run = 0;
#pragma unroll
        for (int i = 0; i < 8; ++i) { woff[i] = run; run += wsum[i]; }
    }
    __syncthreads();
    if (t < BUCKET_SIZE) {
        int incl = scanv[t] + woff[t >> 6];
        int st = s0 + incl - hist[t];
        cur[t] = st;
        int row = (b << BUCKET_BITS) + t;
        if (row < N_NODES) rowseg[row] = make_uint2((unsigned)st, (unsigned)(st + hist[t]));
    }
    __syncthreads();
    for (int i = t; i < cnt; i += 1024) {
        uint2 e = stage[s0 + i];
        int p = atomicAdd(&cur[e.x >> 17], 1);
        csr[p] = make_uint2(e.x & 0x1FFFFu, e.y);
    }
}

// ---------------- fused spmm0 + gemm1: T2 = relu(Ahat @ T) @ W1 ----------------
// 4 waves; wave w gathers rows r0+w*16..+15 into a 16 KB swizzled LDS H-tile,
// then MFMA with W1-frags read per-lane from linear Wt1 (L1-resident).
__global__ __launch_bounds__(256) void fused_spmm_gemm_kernel(
        const uint2* __restrict__ rowseg, const uint2* __restrict__ csr,
        const uint2* __restrict__ T2, const unsigned short* __restrict__ Wt1,
        unsigned short* __restrict__ Tout) {
    __shared__ alignas(16) unsigned short alds[64 * 128];   // 16 KB H tile (swizzled)
    int tid = threadIdx.x;
    int w = tid >> 6, l = tid & 63;
    int half = l >> 5, fl = l & 31;
    long r0 = (long)blockIdx.x * 64;

    for (int t = 0; t < 16; ++t) {
        int lrow = w * 16 + t;
        long row = r0 + lrow;
        uint2 se = (row < N_NODES) ? rowseg[row] : make_uint2(0u, 0u);
        int s = (int)se.x, e = (int)se.y;
        float a0 = 0.f, a1 = 0.f, a2 = 0.f, a3 = 0.f;
        for (int base = s; base < e; base += 64) {
            int cnt = min(64, e - base);
            uint2 ed = csr[base + l];                    // masked by value below
            int col_l = (l < cnt) ? (int)ed.x : 0;
            float val_l = (l < cnt) ? __uint_as_float(ed.y) : 0.f;
            int rounds = (cnt + 7) >> 3;
            for (int r = 0; r < rounds; ++r) {
                int j = r * 8;
                int cc[4]; float vv[4]; uint2 xx[4];
#pragma unroll
                for (int i = 0; i < 4; ++i) {
                    cc[i] = __shfl(col_l, j + 2 * i + half);
                    vv[i] = __shfl(val_l, j + 2 * i + half);
                }
#pragma unroll
                for (int i = 0; i < 4; ++i) xx[i] = T2[cc[i] * 32 + fl];
#pragma unroll
                for (int i = 0; i < 4; ++i) {
                    a0 = fmaf(vv[i], bf_lo(xx[i].x), a0);
                    a1 = fmaf(vv[i], bf_hi(xx[i].x), a1);
                    a2 = fmaf(vv[i], bf_lo(xx[i].y), a2);
                    a3 = fmaf(vv[i], bf_hi(xx[i].y), a3);
                }
            }
        }
        a0 += __shfl_xor(a0, 32);
        a1 += __shfl_xor(a1, 32);
        a2 += __shfl_xor(a2, 32);
        a3 += __shfl_xor(a3, 32);
        if (half == 0) {
            a0 = fmaxf(a0, 0.f); a1 = fmaxf(a1, 0.f);
            a2 = fmaxf(a2, 0.f); a3 = fmaxf(a3, 0.f);
            uint2 o;
            o.x = (unsigned)f2bf(a0) | ((unsigned)f2bf(a1) << 16);
            o.y = (unsigned)f2bf(a2) | ((unsigned)f2bf(a3) << 16);
            *(uint2*)((char*)alds + lrow * 256 + ((fl * 8) ^ ((lrow & 7) << 4))) = o;
        }
    }
    __syncthreads();

    // gemm phase: H tile (LDS) x W1 (global, linear, L1-hot)
    int q = l >> 4, c16 = l & 15;
    f32x4 acc[8] = {};
    int nrow = w * 16 + c16;
    int nswz = (nrow & 7) << 4;
#pragma unroll
    for (int ks = 0; ks < 4; ++ks) {
        int kb = ks * 64 + q * 16;
        short8 bfrag = *(const short8*)((const char*)alds + nrow * 256 + (kb ^ nswz));
#pragma unroll
        for (int fb = 0; fb < 8; ++fb) {
            int frow = fb * 16 + c16;
            short8 afrag = *(const short8*)((const char*)Wt1 + frow * 256 + kb);
            acc[fb] = __builtin_amdgcn_mfma_f32_16x16x32_bf16(afrag, bfrag, acc[fb], 0, 0, 0);
        }
    }

    long node = r0 + w * 16 + c16;
#pragma unroll
    for (int fb = 0; fb < 8; ++fb) {
        uint2 o;
        o.x = (unsigned)f2bf(acc[fb][0]) | ((unsigned)f2bf(acc[fb][1]) << 16);
        o.y = (unsigned)f2bf(acc[fb][2]) | ((unsigned)f2bf(acc[fb][3]) << 16);
        *(uint2*)((char*)Tout + node * 256 + fb * 32 + q * 8) = o;
    }
}

// ---------------- SpMM final + fused ReLU (fp32 out) ----------------
__global__ __launch_bounds__(256) void spmm_relu_kernel(const uint2* __restrict__ rowseg,
                                                        const uint2* __restrict__ csr,
                                                        const uint2* __restrict__ T2,
                                                        float* __restrict__ outv) {
    int wave = threadIdx.x >> 6;
    int lane = threadIdx.x & 63;
    int half = lane >> 5;
    int fl = lane & 31;
    int row = blockIdx.x * 4 + wave;
    uint2 se = rowseg[row];
    int s = (int)se.x, e = (int)se.y;
    float a0 = 0.f, a1 = 0.f, a2 = 0.f, a3 = 0.f;
    for (int base = s; base < e; base += 64) {
        int cnt = min(64, e - base);
        uint2 ed = csr[base + lane];
        int col_l = (lane < cnt) ? (int)ed.x : 0;
        float val_l = (lane < cnt) ? __uint_as_float(ed.y) : 0.f;
        int rounds = (cnt + 7) >> 3;
        for (int r = 0; r < rounds; ++r) {
            int j = r * 8;
            int cc[4]; float vv[4]; uint2 xx[4];
#pragma unroll
            for (int i = 0; i < 4; ++i) {
                cc[i] = __shfl(col_l, j + 2 * i + half);
                vv[i] = __shfl(val_l, j + 2 * i + half);
            }
#pragma unroll
            for (int i = 0; i < 4; ++i) xx[i] = T2[cc[i] * 32 + fl];
#pragma unroll
            for (int i = 0; i < 4; ++i) {
                a0 = fmaf(vv[i], bf_lo(xx[i].x), a0);
                a1 = fmaf(vv[i], bf_hi(xx[i].x), a1);
                a2 = fmaf(vv[i], bf_lo(xx[i].y), a2);
                a3 = fmaf(vv[i], bf_hi(xx[i].y), a3);
            }
        }
    }
    a0 += __shfl_xor(a0, 32);
    a1 += __shfl_xor(a1, 32);
    a2 += __shfl_xor(a2, 32);
    a3 += __shfl_xor(a3, 32);
    if (half == 0) {
        *(float4*)(outv + (size_t)row * 128 + fl * 4) =
            make_float4(fmaxf(a0, 0.f), fmaxf(a1, 0.f), fmaxf(a2, 0.f), fmaxf(a3, 0.f));
    }
}

// ---------------- launch ----------------
extern "C" void kernel_launch(void* const* d_in, const int* in_sizes, int n_in,
                              void* d_out, int out_size, void* d_ws, size_t ws_size,
                              hipStream_t stream) {
    const float* X     = (const float*)d_in[0];
    const float* evals = (const float*)d_in[1];
    const float* W0    = (const float*)d_in[2];
    const float* W1    = (const float*)d_in[3];
    const int* erows   = (const int*)d_in[4];
    const int* ecols   = (const int*)d_in[5];
    float* out = (float*)d_out;

    char* ws = (char*)d_ws;
    size_t off = 0;
    auto carve = [&](size_t bytes) {
        char* p = ws + off;
        off += (bytes + 255) & ~(size_t)255;
        return p;
    };
    unsigned short* T   = (unsigned short*)carve((size_t)M_PAD * F * 2);   // 25.6 MB
    unsigned short* T2  = (unsigned short*)carve((size_t)M_PAD * F * 2);   // 25.6 MB
    unsigned short* Wt0 = (unsigned short*)carve(128 * 128 * 2);
    unsigned short* Wt1 = (unsigned short*)carve(128 * 128 * 2);
    uint2* stage        = (uint2*)carve((size_t)NBUCKETS * BCAP * 8);      // 14.5 MB
    uint2* csr          = (uint2*)carve(((size_t)NBUCKETS * BCAP + 64) * 8);
    uint2* rowseg       = (uint2*)carve((size_t)N_NODES * 8);              // 0.8 MB
    int* bucket_cursor  = (int*)carve((size_t)NBUCKETS * 4);
    (void)ws_size; (void)in_sizes; (void)n_in; (void)out_size;

    // prep: W transposes + cursor zero
    prep_kernel<<<3, 256, 0, stream>>>(W0, W1, Wt0, Wt1, bucket_cursor);

    // K1: binA (first 196 blocks) overlapped with gemm0 (next 1563)
    k1_kernel<<<ABLOCKS + GEMM_GRID, 256, 0, stream>>>(X, Wt0, T, erows, ecols, evals,
                                                       bucket_cursor, stage);

    // binB: finish CSR
    binB_kernel<<<NBUCKETS, 1024, 0, stream>>>(stage, bucket_cursor, csr, rowseg);

    // fused: T2 = relu(Ahat @ T) @ W1
    fused_spmm_gemm_kernel<<<GEMM_GRID, 256, 0, stream>>>(rowseg, csr, (const uint2*)T,
                                                          Wt1, T2);

    // final: out = relu(Ahat @ T2)
    spmm_relu_kernel<<<N_NODES / 4, 256, 0, stream>>>(rowseg, csr, (const uint2*)T2, out);
}

// Round 9
// 184.113 us; speedup vs baseline: 1.2154x; 1.2154x over previous
//
#include <hip/hip_runtime.h>

#define N_NODES 100000
#define N_EDGES 1600000
#define F 128
#define M_PAD 100032          // 1563 blocks * 64 rows
#define GEMM_GRID 1563

#define BUCKET_BITS 9
#define BUCKET_SIZE 512
#define NBUCKETS 196          // ceil(100000/512)
#define BCAP 9216             // fixed bucket capacity (mean 8192, +11 sigma)
#define EPB_A 8192
#define ABLOCKS 196

#define AS1 __attribute__((address_space(1)))
#define AS3 __attribute__((address_space(3)))

typedef __attribute__((ext_vector_type(8))) short short8;
typedef __attribute__((ext_vector_type(4))) float f32x4;

__device__ __forceinline__ float bf_lo(unsigned int u) { return __uint_as_float(u << 16); }
__device__ __forceinline__ float bf_hi(unsigned int u) { return __uint_as_float(u & 0xffff0000u); }
__device__ __forceinline__ unsigned short f2bf(float f) {
    unsigned int u = __float_as_uint(f);
    u += 0x7fffu + ((u >> 16) & 1u);   // round-to-nearest-even
    return (unsigned short)(u >> 16);
}
__device__ __forceinline__ void gload_lds16(const void* g, void* l) {
    __builtin_amdgcn_global_load_lds((const AS1 unsigned int*)g, (AS3 unsigned int*)l, 16, 0, 0);
}

// ---------------- prep: Wt0/Wt1 transposed+swizzled, cursor zero ----------------
__global__ __launch_bounds__(256) void prep_kernel(const float* __restrict__ W0,
                                                   const float* __restrict__ W1,
                                                   unsigned short* __restrict__ Wt0,
                                                   unsigned short* __restrict__ Wt1,
                                                   int* __restrict__ bucket_cursor) {
    int t = threadIdx.x;
    if (blockIdx.x == 2) {
        if (t < NBUCKETS) bucket_cursor[t] = 0;
        return;
    }
    const float* W = (blockIdx.x == 0) ? W0 : W1;
    unsigned short* Wt = (blockIdx.x == 0) ? Wt0 : Wt1;
    int c = t & 127;
    int o0 = (t >> 7) * 8;
    for (int o = o0; o < o0 + 8; ++o) {
        short8 v;
#pragma unroll
        for (int e = 0; e < 8; ++e) v[e] = (short)f2bf(W[(o * 8 + e) * 128 + c]);
        *(short8*)((char*)Wt + c * 256 + ((o * 16) ^ ((c & 7) << 4))) = v;
    }
}

// ---------------- K1: binA (blocks 0..195) + gemm0 (blocks 196..1758) ----------------

__device__ __forceinline__ void binA_body(char* smem, int bid,
                                          const int* __restrict__ rows,
                                          const int* __restrict__ cols,
                                          const float* __restrict__ vals,
                                          int* __restrict__ bucket_cursor,
                                          uint2* __restrict__ stage) {
    int* hist = (int*)smem;
    int* base = hist + NBUCKETS;
    int tid = threadIdx.x;
    int start = bid * EPB_A;
    int cnt = min(EPB_A, N_EDGES - start);
    for (int i = tid; i < NBUCKETS; i += 256) hist[i] = 0;
    __syncthreads();
    for (int i = tid; i < cnt; i += 256) atomicAdd(&hist[rows[start + i] >> BUCKET_BITS], 1);
    __syncthreads();
    for (int i = tid; i < NBUCKETS; i += 256) {
        int h = hist[i];
        base[i] = h ? atomicAdd(&bucket_cursor[i], h) : 0;   // zero-based cursor
        hist[i] = 0;
    }
    __syncthreads();
    for (int i = tid; i < cnt; i += 256) {
        int r = rows[start + i];
        int c = cols[start + i];
        unsigned vb = __float_as_uint(vals[start + i]);
        int b = r >> BUCKET_BITS;
        int p = b * BCAP + base[b] + atomicAdd(&hist[b], 1);
        stage[p] = make_uint2(((unsigned)(r & (BUCKET_SIZE - 1)) << 17) | (unsigned)c, vb);
    }
}

__device__ __forceinline__ void gemm0_body(char* smem, int bid,
                                           const float* __restrict__ X,
                                           const unsigned short* __restrict__ Wt0,
                                           unsigned short* __restrict__ T) {
    unsigned short* wlds = (unsigned short*)smem;            // 32 KB
    unsigned short* alds = (unsigned short*)(smem + 32768);  // 16 KB
    int tid = threadIdx.x;
    int w = tid >> 6, l = tid & 63;
    int q = l >> 4, c16 = l & 15;
    long r0 = (long)bid * 64;

#pragma unroll
    for (int i = 0; i < 8; ++i) {
        int row = w * 32 + i * 4 + q;
        gload_lds16((const char*)Wt0 + row * 256 + c16 * 16,
                    (char*)wlds + (w * 8192 + i * 1024));
    }
#pragma unroll
    for (int i = 0; i < 4; ++i) {
        int row = i * 16 + (tid >> 4);
        int oct = tid & 15;
        long rg = r0 + row;
        if (rg > N_NODES - 1) rg = N_NODES - 1;
        const float4* xp = (const float4*)(X + rg * 128 + oct * 8);
        float4 a = xp[0], bb = xp[1];
        short8 v;
        v[0] = (short)f2bf(a.x); v[1] = (short)f2bf(a.y);
        v[2] = (short)f2bf(a.z); v[3] = (short)f2bf(a.w);
        v[4] = (short)f2bf(bb.x); v[5] = (short)f2bf(bb.y);
        v[6] = (short)f2bf(bb.z); v[7] = (short)f2bf(bb.w);
        *(short8*)((char*)alds + row * 256 + ((oct * 16) ^ ((row & 7) << 4))) = v;
    }
    __syncthreads();

    f32x4 acc[8] = {};
    int nrow = w * 16 + c16;
    int nswz = (nrow & 7) << 4;
#pragma unroll
    for (int ks = 0; ks < 4; ++ks) {
        int kb = ks * 64 + q * 16;
        short8 bfrag = *(const short8*)((const char*)alds + nrow * 256 + (kb ^ nswz));
#pragma unroll
        for (int fb = 0; fb < 8; ++fb) {
            int frow = fb * 16 + c16;
            short8 afrag = *(const short8*)((const char*)wlds + frow * 256 +
                                            (kb ^ ((frow & 7) << 4)));
            acc[fb] = __builtin_amdgcn_mfma_f32_16x16x32_bf16(afrag, bfrag, acc[fb], 0, 0, 0);
        }
    }

    long node = r0 + w * 16 + c16;
#pragma unroll
    for (int fb = 0; fb < 8; ++fb) {
        uint2 o;
        o.x = (unsigned)f2bf(acc[fb][0]) | ((unsigned)f2bf(acc[fb][1]) << 16);
        o.y = (unsigned)f2bf(acc[fb][2]) | ((unsigned)f2bf(acc[fb][3]) << 16);
        *(uint2*)((char*)T + node * 256 + fb * 32 + q * 8) = o;
    }
}

__global__ __launch_bounds__(256) void k1_kernel(const float* __restrict__ X,
                                                 const unsigned short* __restrict__ Wt0,
                                                 unsigned short* __restrict__ T,
                                                 const int* __restrict__ rows,
                                                 const int* __restrict__ cols,
                                                 const float* __restrict__ vals,
                                                 int* __restrict__ bucket_cursor,
                                                 uint2* __restrict__ stage) {
    __shared__ char smem[49152];
    if (blockIdx.x < ABLOCKS) {
        binA_body(smem, blockIdx.x, rows, cols, vals, bucket_cursor, stage);
    } else {
        gemm0_body(smem, blockIdx.x - ABLOCKS, X, Wt0, T);
    }
}

// ---------------- MFMA GEMM (layer 1): T2 = H @ W1, H pre-swizzled bf16 ----------------
__global__ __launch_bounds__(256) void mfma_gemm_kernel(const unsigned short* __restrict__ Av,
                                                        const unsigned short* __restrict__ Wt,
                                                        unsigned short* __restrict__ T) {
    __shared__ alignas(16) unsigned short wlds[128 * 128];  // 32 KB
    __shared__ alignas(16) unsigned short alds[64 * 128];   // 16 KB
    int tid = threadIdx.x;
    int w = tid >> 6, l = tid & 63;
    int q = l >> 4, c16 = l & 15;
    long r0 = (long)blockIdx.x * 64;

#pragma unroll
    for (int i = 0; i < 8; ++i) {
        int row = w * 32 + i * 4 + q;
        gload_lds16((const char*)Wt + row * 256 + c16 * 16,
                    (char*)wlds + (w * 8192 + i * 1024));
    }
#pragma unroll
    for (int i = 0; i < 4; ++i) {
        int row = w * 16 + i * 4 + q;
        gload_lds16((const char*)Av + (r0 + row) * 256 + c16 * 16,
                    (char*)alds + (w * 4096 + i * 1024));
    }
    __syncthreads();

    f32x4 acc[8] = {};
    int nrow = w * 16 + c16;
    int nswz = (nrow & 7) << 4;
#pragma unroll
    for (int ks = 0; ks < 4; ++ks) {
        int kb = ks * 64 + q * 16;
        short8 bfrag = *(const short8*)((const char*)alds + nrow * 256 + (kb ^ nswz));
#pragma unroll
        for (int fb = 0; fb < 8; ++fb) {
            int frow = fb * 16 + c16;
            short8 afrag = *(const short8*)((const char*)wlds + frow * 256 +
                                            (kb ^ ((frow & 7) << 4)));
            acc[fb] = __builtin_amdgcn_mfma_f32_16x16x32_bf16(afrag, bfrag, acc[fb], 0, 0, 0);
        }
    }

    long node = r0 + w * 16 + c16;
#pragma unroll
    for (int fb = 0; fb < 8; ++fb) {
        uint2 o;
        o.x = (unsigned)f2bf(acc[fb][0]) | ((unsigned)f2bf(acc[fb][1]) << 16);
        o.y = (unsigned)f2bf(acc[fb][2]) | ((unsigned)f2bf(acc[fb][3]) << 16);
        *(uint2*)((char*)T + node * 256 + fb * 32 + q * 8) = o;
    }
}

// ---------------- binB: per-bucket counting sort by row ----------------
__global__ __launch_bounds__(1024) void binB_kernel(const uint2* __restrict__ stage,
                                                    const int* __restrict__ bucket_cursor,
                                                    uint2* __restrict__ csr,
                                                    uint2* __restrict__ rowseg) {
    __shared__ int hist[BUCKET_SIZE];
    __shared__ int scanv[BUCKET_SIZE];
    __shared__ int cur[BUCKET_SIZE];
    __shared__ int wsum[8], woff[8];
    int b = blockIdx.x;
    int t = threadIdx.x;
    int s0 = b * BCAP;
    int cnt = bucket_cursor[b];
    if (t < BUCKET_SIZE) hist[t] = 0;
    __syncthreads();
    for (int i = t; i < cnt; i += 1024) atomicAdd(&hist[stage[s0 + i].x >> 17], 1);
    __syncthreads();
    int wid = t >> 6, ln = t & 63;
    if (wid < 8) {
        int v = hist[wid * 64 + ln];
#pragma unroll
        for (int d = 1; d < 64; d <<= 1) {
            int u = __shfl_up(v, d);
            if (ln >= d) v += u;
        }
        if (ln == 63) wsum[wid] = v;
        scanv[wid * 64 + ln] = v;       // per-wave inclusive
    }
    __syncthreads();
    if (t == 0) {
        int run = 0;
#pragma unroll
        for (int i = 0; i < 8; ++i) { woff[i] = run; run += wsum[i]; }
    }
    __syncthreads();
    if (t < BUCKET_SIZE) {
        int incl = scanv[t] + woff[t >> 6];
        int st = s0 + incl - hist[t];
        cur[t] = st;
        int row = (b << BUCKET_BITS) + t;
        if (row < N_NODES) rowseg[row] = make_uint2((unsigned)st, (unsigned)(st + hist[t]));
    }
    __syncthreads();
    for (int i = t; i < cnt; i += 1024) {
        uint2 e = stage[s0 + i];
        int p = atomicAdd(&cur[e.x >> 17], 1);
        csr[p] = make_uint2(e.x & 0x1FFFFu, e.y);
    }
}

// ---------------- SpMM v4 + fused ReLU ----------------
// Half-wave row ownership: lanes 0-31 own one row, lanes 32-63 another (32 lanes
// x uint2 = full 256B T row). No cross-half reduce; full-width stores; 32-edge
// csr tiles. 4-deep gather pipeline per half = 8 independent gathers per wave.
template <bool OUT_BF16>
__global__ __launch_bounds__(256) void spmm_relu_kernel(const uint2* __restrict__ rowseg,
                                                        const uint2* __restrict__ csr,
                                                        const uint2* __restrict__ T2,
                                                        void* __restrict__ outv) {
    int wave = threadIdx.x >> 6;
    int lane = threadIdx.x & 63;
    int half = lane >> 5;
    int fl = lane & 31;
    int row = blockIdx.x * 8 + wave * 2 + half;
    uint2 se = rowseg[row];
    int s = (int)se.x, e = (int)se.y;
    float a0 = 0.f, a1 = 0.f, a2 = 0.f, a3 = 0.f;
    for (int base = s; base < e; base += 32) {
        int cnt = min(32, e - base);
        uint2 ed = csr[base + fl];                      // slack-covered over-read
        int col_l = (fl < cnt) ? (int)ed.x : 0;
        float val_l = (fl < cnt) ? __uint_as_float(ed.y) : 0.f;
        int rounds = (cnt + 3) >> 2;
        for (int r = 0; r < rounds; ++r) {
            int j = r * 4;
            int cc[4]; float vv[4]; uint2 xx[4];
#pragma unroll
            for (int i = 0; i < 4; ++i) {
                cc[i] = __shfl(col_l, j + i, 32);       // within own half
                vv[i] = __shfl(val_l, j + i, 32);
            }
#pragma unroll
            for (int i = 0; i < 4; ++i) xx[i] = T2[cc[i] * 32 + fl];
#pragma unroll
            for (int i = 0; i < 4; ++i) {
                a0 = fmaf(vv[i], bf_lo(xx[i].x), a0);
                a1 = fmaf(vv[i], bf_hi(xx[i].x), a1);
                a2 = fmaf(vv[i], bf_lo(xx[i].y), a2);
                a3 = fmaf(vv[i], bf_hi(xx[i].y), a3);
            }
        }
    }
    a0 = fmaxf(a0, 0.f); a1 = fmaxf(a1, 0.f);
    a2 = fmaxf(a2, 0.f); a3 = fmaxf(a3, 0.f);
    if constexpr (OUT_BF16) {
        uint2 o;
        o.x = (unsigned)f2bf(a0) | ((unsigned)f2bf(a1) << 16);
        o.y = (unsigned)f2bf(a2) | ((unsigned)f2bf(a3) << 16);
        *(uint2*)((char*)outv + (size_t)row * 256 + ((fl * 8) ^ ((row & 7) << 4))) = o;
    } else {
        *(float4*)((float*)outv + (size_t)row * 128 + fl * 4) =
            make_float4(a0, a1, a2, a3);
    }
}

// ---------------- launch ----------------
extern "C" void kernel_launch(void* const* d_in, const int* in_sizes, int n_in,
                              void* d_out, int out_size, void* d_ws, size_t ws_size,
                              hipStream_t stream) {
    const float* X     = (const float*)d_in[0];
    const float* evals = (const float*)d_in[1];
    const float* W0    = (const float*)d_in[2];
    const float* W1    = (const float*)d_in[3];
    const int* erows   = (const int*)d_in[4];
    const int* ecols   = (const int*)d_in[5];
    float* out = (float*)d_out;

    char* ws = (char*)d_ws;
    size_t off = 0;
    auto carve = [&](size_t bytes) {
        char* p = ws + off;
        off += (bytes + 255) & ~(size_t)255;
        return p;
    };
    unsigned short* T   = (unsigned short*)carve((size_t)M_PAD * F * 2);   // 25.6 MB
    unsigned short* H   = (unsigned short*)carve((size_t)M_PAD * F * 2);   // 25.6 MB
    unsigned short* Wt0 = (unsigned short*)carve(128 * 128 * 2);
    unsigned short* Wt1 = (unsigned short*)carve(128 * 128 * 2);
    uint2* stage        = (uint2*)carve((size_t)NBUCKETS * BCAP * 8);      // 14.5 MB
    uint2* csr          = (uint2*)carve(((size_t)NBUCKETS * BCAP + 64) * 8);
    uint2* rowseg       = (uint2*)carve((size_t)N_NODES * 8);              // 0.8 MB
    int* bucket_cursor  = (int*)carve((size_t)NBUCKETS * 4);
    (void)ws_size; (void)in_sizes; (void)n_in; (void)out_size;

    // prep: W transposes + cursor zero
    prep_kernel<<<3, 256, 0, stream>>>(W0, W1, Wt0, Wt1, bucket_cursor);

    // K1: binA (first 196 blocks) overlapped with gemm0 (next 1563)
    k1_kernel<<<ABLOCKS + GEMM_GRID, 256, 0, stream>>>(X, Wt0, T, erows, ecols, evals,
                                                       bucket_cursor, stage);

    // binB: finish CSR
    binB_kernel<<<NBUCKETS, 1024, 0, stream>>>(stage, bucket_cursor, csr, rowseg);

    // layer 0 spmm: H = relu(Ahat @ T)   (H bf16, pre-swizzled)
    spmm_relu_kernel<true><<<N_NODES / 8, 256, 0, stream>>>(rowseg, csr,
                                                            (const uint2*)T, H);

    // layer 1 gemm: T = H @ W1
    mfma_gemm_kernel<<<GEMM_GRID, 256, 0, stream>>>(H, Wt1, T);

    // layer 1 spmm: out = relu(Ahat @ T)
    spmm_relu_kernel<false><<<N_NODES / 8, 256, 0, stream>>>(rowseg, csr,
                                                             (const uint2*)T, out);
}